// Round 5
// baseline (1455.150 us; speedup 1.0000x reference)
//
#include <hip/hip_runtime.h>
#include <math.h>

#define B_  2
#define N_  384
#define C_  256
#define H_  4
#define D_  64
#define NBH (B_*H_)            // 8
#define TSZ (NBH*N_*D_)        // 196608 floats per projected tensor [bh][n][d]
#define ESZ (NBH*N_*N_)        // 1179648 elems per logit matrix [bh][i][j]
#define SCALE 0.125f           // D^-0.5
#define NWSLICE (NBH*N_*68)    // 208896 floats per numw partial

typedef _Float16 f16;
typedef f16  f16x8 __attribute__((ext_vector_type(8)));
typedef f16  f16x4 __attribute__((ext_vector_type(4)));
typedef float f32x4 __attribute__((ext_vector_type(4)));

// ---------------------------------------------------------------------------
// Kernel 1: projection (unchanged). proj[t][bh][n][d], t in {a,b,c,v1,v2}, f32.
// ---------------------------------------------------------------------------
__global__ __launch_bounds__(256) void proj_kernel(const float* __restrict__ x,
                                                   const float* __restrict__ W,
                                                   float* __restrict__ proj) {
    __shared__ float Xs[32][68];
    __shared__ float Ws[32][68];
    const int tid = threadIdx.x;
    const int tx = tid & 15, ty = tid >> 4;
    const int m0 = blockIdx.x * 64;
    const int c0 = blockIdx.y * 64;
    const int t  = c0 >> 8;
    const int wbase = ((t >= 3) ? (t + 3) : t) * 256;

    float acc[4][4] = {{0.f}};
    for (int k0 = 0; k0 < 256; k0 += 32) {
        __syncthreads();
#pragma unroll
        for (int l = 0; l < 8; ++l) {
            const int idx = l * 256 + tid;
            const int mi = idx >> 5, kk = idx & 31;
            Xs[kk][mi] = x[(m0 + mi) * 256 + k0 + kk];
            const int rem = (c0 + mi) & 255;
            Ws[kk][mi] = W[(wbase + rem) * 256 + k0 + kk];
        }
        __syncthreads();
#pragma unroll
        for (int kk = 0; kk < 32; ++kk) {
            const float4 xf = *(const float4*)&Xs[kk][ty * 4];
            const float4 wf = *(const float4*)&Ws[kk][tx * 4];
            const float xa[4] = {xf.x, xf.y, xf.z, xf.w};
            const float wa[4] = {wf.x, wf.y, wf.z, wf.w};
#pragma unroll
            for (int q = 0; q < 4; ++q)
#pragma unroll
                for (int p = 0; p < 4; ++p)
                    acc[q][p] += xa[q] * wa[p];
        }
    }
#pragma unroll
    for (int q = 0; q < 4; ++q) {
        const int r = m0 + ty * 4 + q;
        const int b = r / N_;
        const int n = r - b * N_;
#pragma unroll
        for (int p = 0; p < 4; ++p) {
            const int rem = (c0 + tx * 4 + p) & 255;
            const int h = rem >> 6, d = rem & 63;
            proj[t * TSZ + ((b * H_ + h) * N_ + n) * D_ + d] = acc[q][p];
        }
    }
}

// ---------------------------------------------------------------------------
// Kernel 2: exp-logit matrices, mixed-dtype outputs (unchanged).
// ---------------------------------------------------------------------------
__global__ __launch_bounds__(256) void logits_kernel(const float* __restrict__ proj,
                                                     f16* __restrict__ eabt16,
                                                     float* __restrict__ ecd,
                                                     f16* __restrict__ eef16) {
    __shared__ float Xs[32][68];
    __shared__ float Ys[32][68];
    const int tid = threadIdx.x;
    const int tx = tid & 15, ty = tid >> 4;
    const int i0 = blockIdx.x * 64, j0 = blockIdx.y * 64;
    const int q  = blockIdx.z >> 3;
    const int bh = blockIdx.z & 7;
    const int xt = q;
    const int yt = (q == 2) ? 0 : (q + 1);
    const float* Xp = proj + xt * TSZ + bh * N_ * D_;
    const float* Yp = proj + yt * TSZ + bh * N_ * D_;

    float acc[4][4] = {{0.f}};
    for (int k0 = 0; k0 < 64; k0 += 32) {
        __syncthreads();
#pragma unroll
        for (int l = 0; l < 8; ++l) {
            const int idx = l * 256 + tid;
            const int mi = idx >> 5, kk = idx & 31;
            Xs[kk][mi] = Xp[(i0 + mi) * 64 + k0 + kk];
            Ys[kk][mi] = Yp[(j0 + mi) * 64 + k0 + kk];
        }
        __syncthreads();
#pragma unroll
        for (int kk = 0; kk < 32; ++kk) {
            const float4 xf = *(const float4*)&Xs[kk][ty * 4];
            const float4 yf = *(const float4*)&Ys[kk][tx * 4];
            const float xa[4] = {xf.x, xf.y, xf.z, xf.w};
            const float ya[4] = {yf.x, yf.y, yf.z, yf.w};
#pragma unroll
            for (int qq = 0; qq < 4; ++qq)
#pragma unroll
                for (int p = 0; p < 4; ++p)
                    acc[qq][p] += xa[qq] * ya[p];
        }
    }
#pragma unroll
    for (int qq = 0; qq < 4; ++qq)
#pragma unroll
        for (int p = 0; p < 4; ++p) {
            const float e = expf(acc[qq][p] * SCALE);
            const int ii = i0 + ty * 4 + qq;
            const int jj = j0 + tx * 4 + p;
            if (q == 0)      eabt16[(size_t)bh * N_ * N_ + jj * N_ + ii] = (f16)e;
            else if (q == 1) ecd   [(size_t)bh * N_ * N_ + ii * N_ + jj] = e;
            else             eef16 [(size_t)bh * N_ * N_ + ii * N_ + jj] = (f16)e;
        }
}

// ---------------------------------------------------------------------------
// Kernel 3 (dominant), MFMA f16.
// Round-5: keep round-4's proven ping-pong + T14 prefetch (per-wave eff 2x),
// recover residency lost to round-4's 228 VGPR + 80896 LDS (1 block/CU):
//  * j-tile 64 -> 32: es/ab ping-pong buffers 4KB each, prefetch = 1 uint4
//    per thread per buffer (round-4 had 2) -- big cut in live VGPRs.
//  * pitch padding (PIT 72) replaced by T2 XOR swizzle (byte ^= (row&7)<<4,
//    same involution on write and read; all accesses stay 8/16B aligned):
//    pitch 64, us shrinks 36864 -> 32768, conflict-free ds_read_b128.
//  * v1s LDS dropped: v1 = 2 scalar prefetched loads/jt with the T14 batch
//    (outside the unrolled fold -- avoids round-3's hoisting blowup).
//  * LDS total 50176 -> 3 blocks/CU; __launch_bounds__(256,3) caps regs at
//    170 (est. natural ~140 -- 20+ headroom, unlike round-1's 128-vs-200).
//  * 2-way kt split back (1632 blocks = 2.1 fill rounds at 3 blocks/CU).
// ---------------------------------------------------------------------------
__global__ __launch_bounds__(256, 3) void triplet_mfma_kernel(
        const f16*  __restrict__ eabt,   // [bh][j][i]
        const float* __restrict__ ecd,   // [bh][i][k]
        const f16*  __restrict__ eef,    // [bh][j][k]
        const float* __restrict__ v1,    // [bh][n][64]
        const float* __restrict__ v2,    // [bh][n][64]
        float* __restrict__ num0,        // [bh][i][68] partial (kt 0..2)
        float* __restrict__ num1) {      // [bh][i][68] partial (kt 3..5)
    // LDS map (bytes):
    //   [    0, 32768) us   : 4 d-slices x 64 rows x 128B (XOR-swizzled)
    //   [32768, 40960) es2  : 2 bufs x 32 rows x 128B (XOR-swizzled)
    //   [40960, 49152) ab2  : 2 bufs x 32 rows x 128B (XOR-swizzled)
    //   [49152, 50176) v2k  : float[4][64]
    __shared__ __align__(16) unsigned char smem[50176];
    float* v2k = (float*)(smem + 49152);

    const int tid  = threadIdx.x;
    const int lane = tid & 63;
    const int w    = tid >> 6;        // wave id = d slot
    const int quad = lane >> 4;
    const int lr   = lane & 15;
    const int i0 = blockIdx.x * 64;
    const int dg = blockIdx.y;        // 0..16
    const int zz = blockIdx.z;
    const int bh    = zz & 7;
    const int split = zz >> 3;        // 0 or 1 -> kt half
    const int dd = dg * 4 + w;        // 0..67 (>=64: denominator)

    const f16*   eabtb = eabt + (size_t)bh * N_ * N_;
    const float* ecdb  = ecd  + (size_t)bh * N_ * N_;
    const f16*   eefb  = eef  + (size_t)bh * N_ * N_;
    const float* v1b   = v1 + (size_t)bh * N_ * D_;
    const float* v2b   = v2 + (size_t)bh * N_ * D_;
    float* numout = split ? num1 : num0;

    float numacc[16];
#pragma unroll
    for (int r = 0; r < 16; ++r) numacc[r] = 0.f;

    const f32x4 zero4 = {0.f, 0.f, 0.f, 0.f};

    // thread roles
    const int brow = tid >> 4;        // 0..15 (U-build row group)
    const int tx   = tid & 15;        // U-build k-col group (x4 floats)
    const int srow = tid >> 3;        // 0..31 (es/ab staging row)
    const int sblk = tid & 7;         // 0..7
    const int sw   = (lr & 7) << 4;   // read-side XOR swizzle
    const int soff = (srow * 128 + sblk * 16) ^ ((srow & 7) << 4);  // write-side

    const int ktbeg = split * 3;
    for (int kt = ktbeg; kt < ktbeg + 3; ++kt) {
        const int k0 = kt * 64;
        // stage v2 chunk: v2k[c*64 + k]. Prior readers (last kt's U-build)
        // finished many barriers ago.
        {
            const int c = tid >> 6, k = tid & 63;
            const int d2 = dg * 4 + c;
            v2k[c * 64 + k] = (d2 < 64) ? v2b[(k0 + k) * 64 + d2] : 1.0f;
        }
        __syncthreads();              // v2k ready
        // T14: issue jt=0 tile loads now -- latency hides under U-build VALU
        uint4 pe = *(const uint4*)(eefb  + srow * N_ + k0 + sblk * 8);
        uint4 pa = *(const uint4*)(eabtb + srow * N_ + i0 + sblk * 8);
        float v1n0 = (dd < 64) ? v1b[lr * 64 + dd] : 1.0f;
        float v1n1 = (dd < 64) ? v1b[(16 + lr) * 64 + dd] : 1.0f;
        // build U16[d][64 rows][64 k] = f16(eCD * v2col), swizzled
#pragma unroll
        for (int it = 0; it < 4; ++it) {
            const int row = it * 16 + brow;
            const float4 c4 = *(const float4*)&ecdb[(i0 + row) * N_ + k0 + tx * 4];
            const int rowoff = (row * 128 + tx * 8) ^ ((row & 7) << 4);
#pragma unroll
            for (int d = 0; d < 4; ++d) {
                const float4 w4 = *(const float4*)&v2k[d * 64 + tx * 4];
                union { f16 h[4]; unsigned long long u; } pk;
                pk.h[0] = (f16)(c4.x * w4.x);
                pk.h[1] = (f16)(c4.y * w4.y);
                pk.h[2] = (f16)(c4.z * w4.z);
                pk.h[3] = (f16)(c4.w * w4.w);
                *(unsigned long long*)(smem + d * 8192 + rowoff) = pk.u;
            }
        }
        // write jt=0 tile into buffer 0
        *(uint4*)(smem + 32768 + soff) = pe;
        *(uint4*)(smem + 40960 + soff) = pa;
        __syncthreads();              // us + buf0 ready
        // A-frags for this wave's d, all 4 i-subtiles x 2 k-halves
        f16x8 af[4][2];
#pragma unroll
        for (int isub = 0; isub < 4; ++isub) {
            const int row = isub * 16 + lr;
#pragma unroll
            for (int ks = 0; ks < 2; ++ks)
                af[isub][ks] = *(const f16x8*)(smem + w * 8192 + row * 128 +
                                               (((ks * 4 + quad) * 16) ^ sw));
        }

        for (int jt = 0; jt < 12; ++jt) {
            const int j0 = jt * 32;
            const int p  = jt & 1;
            const unsigned char* esb = smem + 32768 + p * 4096;
            const unsigned char* abb = smem + 40960 + p * 4096;
            const float v1c0 = v1n0, v1c1 = v1n1;
            // T14: issue NEXT tile's global loads before compute
            uint4 qe, qa;
            if (jt < 11) {
                const int jn = j0 + 32;
                qe = *(const uint4*)(eefb  + (jn + srow) * N_ + k0 + sblk * 8);
                qa = *(const uint4*)(eabtb + (jn + srow) * N_ + i0 + sblk * 8);
                v1n0 = (dd < 64) ? v1b[(jn + lr) * 64 + dd] : 1.0f;
                v1n1 = (dd < 64) ? v1b[(jn + 16 + lr) * 64 + dd] : 1.0f;
            }
            // compute from buffer p (MFMA + immediate fold of partial R)
#pragma unroll
            for (int js = 0; js < 2; ++js) {
                const int row = js * 16 + lr;
                const f16x8 bf0 = *(const f16x8*)(esb + row * 128 + ((quad * 16) ^ sw));
                const f16x8 bf1 = *(const f16x8*)(esb + row * 128 + (((4 + quad) * 16) ^ sw));
                const float v1v = js ? v1c1 : v1c0;
#pragma unroll
                for (int isub = 0; isub < 4; ++isub) {
                    f32x4 t;
                    t = __builtin_amdgcn_mfma_f32_16x16x32_f16(af[isub][0], bf0, zero4, 0, 0, 0);
                    t = __builtin_amdgcn_mfma_f32_16x16x32_f16(af[isub][1], bf1, t, 0, 0, 0);
                    const f16x4 ab = *(const f16x4*)(abb + row * 128 +
                                                     ((isub * 32 + quad * 8) ^ sw));
#pragma unroll
                    for (int q = 0; q < 4; ++q)
                        numacc[isub * 4 + q] += (float)ab[q] * (v1v * t[q]);
                }
            }
            // write next tile into buffer p^1 (readers done at jt-1's barrier)
            if (jt < 11) {
                *(uint4*)(smem + 32768 + (p ^ 1) * 4096 + soff) = qe;
                *(uint4*)(smem + 40960 + (p ^ 1) * 4096 + soff) = qa;
            }
            __syncthreads();          // one barrier per jt
        }
    }
    // reduce the j-residues (low 4 lane bits) and write
#pragma unroll
    for (int r = 0; r < 16; ++r) {
        float v = numacc[r];
        v += __shfl_xor(v, 1);
        v += __shfl_xor(v, 2);
        v += __shfl_xor(v, 4);
        v += __shfl_xor(v, 8);
        numacc[r] = v;
    }
    if (lr == 0) {
#pragma unroll
        for (int r = 0; r < 16; ++r) {
            const int i = (r >> 2) * 16 + quad * 4 + (r & 3);
            numout[((size_t)bh * N_ + i0 + i) * 68 + dd] = numacc[r];
        }
    }
}

// ---------------------------------------------------------------------------
// Kernel 4: out[b,n,h*64+d] = (num0+num1)[bh,n,d] / (num0+num1)[bh,n,64]
// ---------------------------------------------------------------------------
__global__ __launch_bounds__(256) void finalize_kernel(const float* __restrict__ num0,
                                                       const float* __restrict__ num1,
                                                       float* __restrict__ out) {
    const int o = blockIdx.x * 256 + threadIdx.x;
    const int b = o / (N_ * C_);
    const int rem = o - b * (N_ * C_);
    const int n = rem >> 8;
    const int cc = rem & 255;
    const int h = cc >> 6, d = cc & 63;
    const size_t base = (((size_t)b * H_ + h) * N_ + n) * 68;
    const float nmr = num0[base + d]  + num1[base + d];
    const float dnr = num0[base + 64] + num1[base + 64];
    out[o] = nmr / dnr;
}

extern "C" void kernel_launch(void* const* d_in, const int* in_sizes, int n_in,
                              void* d_out, int out_size, void* d_ws, size_t ws_size,
                              hipStream_t stream) {
    const float* x = (const float*)d_in[0];
    const float* W = (const float*)d_in[1];
    float* ws    = (float*)d_ws;
    float* proj  = ws;                         // 5*TSZ f32
    float* ecd   = ws + 5 * TSZ;               // ESZ f32
    float* num1  = ecd + ESZ;                  // NWSLICE f32 (kt 3..5 partial)
    f16*   eabt  = (f16*)(num1 + NWSLICE);     // ESZ f16
    f16*   eef   = eabt + ESZ;                 // ESZ f16
    // num0 reuses proj slots 0-1 (a,b) -- dead after logits_kernel.
    // NWSLICE (208896) < 2*TSZ (393216), so it fits without touching v1/v2.
    float* num0  = ws;
    // total ws usage unchanged: ~14.2 MB

    proj_kernel<<<dim3(12, 20), 256, 0, stream>>>(x, W, proj);
    logits_kernel<<<dim3(6, 6, 24), 256, 0, stream>>>(proj, eabt, ecd, eef);
    triplet_mfma_kernel<<<dim3(6, 17, 16), 256, 0, stream>>>(
        eabt, ecd, eef, proj + 3 * TSZ, proj + 4 * TSZ, num0, num1);
    finalize_kernel<<<dim3(768), 256, 0, stream>>>(num0, num1, (float*)d_out);
}

// Round 6
// 342.056 us; speedup vs baseline: 4.2541x; 4.2541x over previous
//
#include <hip/hip_runtime.h>
#include <math.h>

#define B_  2
#define N_  384
#define C_  256
#define H_  4
#define D_  64
#define NBH (B_*H_)            // 8
#define TSZ (NBH*N_*D_)        // 196608 floats per projected tensor [bh][n][d]
#define ESZ (NBH*N_*N_)        // 1179648 elems per logit matrix [bh][i][j]
#define SCALE 0.125f           // D^-0.5

typedef _Float16 f16;
typedef f16  f16x8 __attribute__((ext_vector_type(8)));
typedef f16  f16x4 __attribute__((ext_vector_type(4)));
typedef float f32x4 __attribute__((ext_vector_type(4)));

// ---------------------------------------------------------------------------
// Kernel 1: projection (unchanged). proj[t][bh][n][d], t in {a,b,c,v1,v2}, f32.
// ---------------------------------------------------------------------------
__global__ __launch_bounds__(256) void proj_kernel(const float* __restrict__ x,
                                                   const float* __restrict__ W,
                                                   float* __restrict__ proj) {
    __shared__ float Xs[32][68];
    __shared__ float Ws[32][68];
    const int tid = threadIdx.x;
    const int tx = tid & 15, ty = tid >> 4;
    const int m0 = blockIdx.x * 64;
    const int c0 = blockIdx.y * 64;
    const int t  = c0 >> 8;
    const int wbase = ((t >= 3) ? (t + 3) : t) * 256;

    float acc[4][4] = {{0.f}};
    for (int k0 = 0; k0 < 256; k0 += 32) {
        __syncthreads();
#pragma unroll
        for (int l = 0; l < 8; ++l) {
            const int idx = l * 256 + tid;
            const int mi = idx >> 5, kk = idx & 31;
            Xs[kk][mi] = x[(m0 + mi) * 256 + k0 + kk];
            const int rem = (c0 + mi) & 255;
            Ws[kk][mi] = W[(wbase + rem) * 256 + k0 + kk];
        }
        __syncthreads();
#pragma unroll
        for (int kk = 0; kk < 32; ++kk) {
            const float4 xf = *(const float4*)&Xs[kk][ty * 4];
            const float4 wf = *(const float4*)&Ws[kk][tx * 4];
            const float xa[4] = {xf.x, xf.y, xf.z, xf.w};
            const float wa[4] = {wf.x, wf.y, wf.z, wf.w};
#pragma unroll
            for (int q = 0; q < 4; ++q)
#pragma unroll
                for (int p = 0; p < 4; ++p)
                    acc[q][p] += xa[q] * wa[p];
        }
    }
#pragma unroll
    for (int q = 0; q < 4; ++q) {
        const int r = m0 + ty * 4 + q;
        const int b = r / N_;
        const int n = r - b * N_;
#pragma unroll
        for (int p = 0; p < 4; ++p) {
            const int rem = (c0 + tx * 4 + p) & 255;
            const int h = rem >> 6, d = rem & 63;
            proj[t * TSZ + ((b * H_ + h) * N_ + n) * D_ + d] = acc[q][p];
        }
    }
}

// ---------------------------------------------------------------------------
// Kernel 2: exp-logit matrices, mixed-dtype outputs (unchanged).
// ---------------------------------------------------------------------------
__global__ __launch_bounds__(256) void logits_kernel(const float* __restrict__ proj,
                                                     f16* __restrict__ eabt16,
                                                     float* __restrict__ ecd,
                                                     f16* __restrict__ eef16) {
    __shared__ float Xs[32][68];
    __shared__ float Ys[32][68];
    const int tid = threadIdx.x;
    const int tx = tid & 15, ty = tid >> 4;
    const int i0 = blockIdx.x * 64, j0 = blockIdx.y * 64;
    const int q  = blockIdx.z >> 3;
    const int bh = blockIdx.z & 7;
    const int xt = q;
    const int yt = (q == 2) ? 0 : (q + 1);
    const float* Xp = proj + xt * TSZ + bh * N_ * D_;
    const float* Yp = proj + yt * TSZ + bh * N_ * D_;

    float acc[4][4] = {{0.f}};
    for (int k0 = 0; k0 < 64; k0 += 32) {
        __syncthreads();
#pragma unroll
        for (int l = 0; l < 8; ++l) {
            const int idx = l * 256 + tid;
            const int mi = idx >> 5, kk = idx & 31;
            Xs[kk][mi] = Xp[(i0 + mi) * 64 + k0 + kk];
            Ys[kk][mi] = Yp[(j0 + mi) * 64 + k0 + kk];
        }
        __syncthreads();
#pragma unroll
        for (int kk = 0; kk < 32; ++kk) {
            const float4 xf = *(const float4*)&Xs[kk][ty * 4];
            const float4 yf = *(const float4*)&Ys[kk][tx * 4];
            const float xa[4] = {xf.x, xf.y, xf.z, xf.w};
            const float ya[4] = {yf.x, yf.y, yf.z, yf.w};
#pragma unroll
            for (int qq = 0; qq < 4; ++qq)
#pragma unroll
                for (int p = 0; p < 4; ++p)
                    acc[qq][p] += xa[qq] * ya[p];
        }
    }
#pragma unroll
    for (int qq = 0; qq < 4; ++qq)
#pragma unroll
        for (int p = 0; p < 4; ++p) {
            const float e = expf(acc[qq][p] * SCALE);
            const int ii = i0 + ty * 4 + qq;
            const int jj = j0 + tx * 4 + p;
            if (q == 0)      eabt16[(size_t)bh * N_ * N_ + jj * N_ + ii] = (f16)e;
            else if (q == 1) ecd   [(size_t)bh * N_ * N_ + ii * N_ + jj] = e;
            else             eef16 [(size_t)bh * N_ * N_ + ii * N_ + jj] = (f16)e;
        }
}

// ---------------------------------------------------------------------------
// Kernel 3 (dominant), MFMA f16.
// Round-6 = round-0 data paths EXACTLY (all-LDS inner loop, no prefetch regs,
// NO launch-bounds cap -- rounds 1/3/5 all spilled from register pressure),
// with residency raised purely via LDS:
//  * T2 XOR swizzle (byte ^= (row&7)<<4, same involution write & read)
//    replaces PIT=72 padding: pitch 128B, bank-uniform for all access
//    patterns here (verified per-pattern: b64/b128 reads & writes).
//  * i-tile 64 -> 32: us halves to 16KB, af 32->16 VGPR, numacc 16->8.
//  * v1 staged per-jt as [64][4] (1KB) instead of whole-column 6KB.
//  * LDS total 34816 B -> 4 blocks/CU (vs round-0's 2). VGPR est ~80.
//  * grid 12x17x8 = 1632 blocks, capacity 1024 -> 1.6 fill rounds.
// ---------------------------------------------------------------------------
__global__ __launch_bounds__(256) void triplet_mfma_kernel(
        const f16*  __restrict__ eabt,   // [bh][j][i]
        const float* __restrict__ ecd,   // [bh][i][k]
        const f16*  __restrict__ eef,    // [bh][j][k]
        const float* __restrict__ v1,    // [bh][n][64]
        const float* __restrict__ v2,    // [bh][n][64]
        float* __restrict__ numout) {    // [bh][i][68]
    // LDS map (bytes):
    //   [    0, 16384) us   : 4 d-slices x 32 rows x 128B (XOR-swizzled)
    //   [16384, 24576) es   : 64 rows x 128B (XOR-swizzled)
    //   [24576, 32768) abts : 64 rows x 128B (XOR-swizzled)
    //   [32768, 33792) v1t  : float[64][4]
    //   [33792, 34816) v2k  : float[4][64]
    __shared__ __align__(16) unsigned char smem[34816];
    float* v1t = (float*)(smem + 32768);
    float* v2k = (float*)(smem + 33792);

    const int tid  = threadIdx.x;
    const int lane = tid & 63;
    const int w    = tid >> 6;        // wave id = d slot
    const int quad = lane >> 4;
    const int lr   = lane & 15;
    const int i0 = blockIdx.x * 32;
    const int dg = blockIdx.y;        // 0..16
    const int bh = blockIdx.z;
    const int dd = dg * 4 + w;        // 0..67 (>=64: denominator)

    const f16*   eabtb = eabt + (size_t)bh * N_ * N_;
    const float* ecdb  = ecd  + (size_t)bh * N_ * N_;
    const f16*   eefb  = eef  + (size_t)bh * N_ * N_;
    const float* v1b   = v1 + (size_t)bh * N_ * D_;
    const float* v2b   = v2 + (size_t)bh * N_ * D_;

    float numacc[8];
#pragma unroll
    for (int r = 0; r < 8; ++r) numacc[r] = 0.f;

    const f32x4 zero4 = {0.f, 0.f, 0.f, 0.f};

    // thread roles
    const int brow = tid >> 4;        // 0..15 (U-build row)
    const int tx   = tid & 15;        // U-build k-col group (x4 floats)
    const int srow = tid >> 3;        // 0..31 (es/abts staging row)
    const int sblk = tid & 7;         // 0..7
    const int sw   = (lr & 7) << 4;   // read-side XOR (row low bits == lr&7)

    for (int kt = 0; kt < 6; ++kt) {
        const int k0 = kt * 64;
        __syncthreads();              // prior kt fully consumed
        // stage v2 chunk: v2k[c*64 + k]
        {
            const int c = tid >> 6, k = tid & 63;
            const int d2 = dg * 4 + c;
            v2k[c * 64 + k] = (d2 < 64) ? v2b[(k0 + k) * 64 + d2] : 1.0f;
        }
        __syncthreads();              // v2k ready
        // build U16[d][32 rows][64 k] = f16(eCD * v2col), swizzled
#pragma unroll
        for (int it = 0; it < 2; ++it) {
            const int row = it * 16 + brow;
            const float4 c4 = *(const float4*)&ecdb[(i0 + row) * N_ + k0 + tx * 4];
            const int rowoff = (row * 128 + tx * 8) ^ ((row & 7) << 4);
#pragma unroll
            for (int d = 0; d < 4; ++d) {
                const float4 w4 = *(const float4*)&v2k[d * 64 + tx * 4];
                union { f16 h[4]; unsigned long long u; } pk;
                pk.h[0] = (f16)(c4.x * w4.x);
                pk.h[1] = (f16)(c4.y * w4.y);
                pk.h[2] = (f16)(c4.z * w4.z);
                pk.h[3] = (f16)(c4.w * w4.w);
                *(unsigned long long*)(smem + d * 4096 + rowoff) = pk.u;
            }
        }
        __syncthreads();              // us ready
        // A-frags for this wave's d: 2 i-subtiles x 2 k-halves
        f16x8 af[2][2];
#pragma unroll
        for (int isub = 0; isub < 2; ++isub) {
            const int row = isub * 16 + lr;
#pragma unroll
            for (int ks = 0; ks < 2; ++ks)
                af[isub][ks] = *(const f16x8*)(smem + w * 4096 + row * 128 +
                                               (((ks * 4 + quad) * 16) ^ sw));
        }

        for (int jt = 0; jt < 6; ++jt) {
            const int j0 = jt * 64;
            __syncthreads();          // prior readers of es/abts/v1t done
#pragma unroll
            for (int it = 0; it < 2; ++it) {
                const int row = it * 32 + srow;
                const int off = (row * 128 + sblk * 16) ^ ((row & 7) << 4);
                *(uint4*)(smem + 16384 + off) =
                    *(const uint4*)(eefb  + (j0 + row) * N_ + k0 + sblk * 8);
                *(uint4*)(smem + 24576 + off) =
                    *(const uint4*)(eabtb + (j0 + row) * N_ + i0 + sblk * 8);
            }
            {   // v1t[j][c] for this jt's 64 j-rows
                const int j = tid >> 2, c = tid & 3;
                const int d2 = dg * 4 + c;
                v1t[tid] = (d2 < 64) ? v1b[(j0 + j) * 64 + d2] : 1.0f;
            }
            __syncthreads();
            // MFMA + immediate fold of the partial R tile
#pragma unroll
            for (int js = 0; js < 4; ++js) {
                const int row = js * 16 + lr;
                const int ro  = row * 128;
                const f16x8 bf0 = *(const f16x8*)(smem + 16384 + ro + ((quad * 16) ^ sw));
                const f16x8 bf1 = *(const f16x8*)(smem + 16384 + ro + (((4 + quad) * 16) ^ sw));
                const float v1v = v1t[row * 4 + w];
#pragma unroll
                for (int isub = 0; isub < 2; ++isub) {
                    f32x4 t;
                    t = __builtin_amdgcn_mfma_f32_16x16x32_f16(af[isub][0], bf0, zero4, 0, 0, 0);
                    t = __builtin_amdgcn_mfma_f32_16x16x32_f16(af[isub][1], bf1, t, 0, 0, 0);
                    const f16x4 ab = *(const f16x4*)(smem + 24576 + ro +
                                                     ((isub * 32 + quad * 8) ^ sw));
#pragma unroll
                    for (int q = 0; q < 4; ++q)
                        numacc[isub * 4 + q] += (float)ab[q] * (v1v * t[q]);
                }
            }
        }
    }
    // reduce the j-residues (low 4 lane bits) and write
#pragma unroll
    for (int r = 0; r < 8; ++r) {
        float v = numacc[r];
        v += __shfl_xor(v, 1);
        v += __shfl_xor(v, 2);
        v += __shfl_xor(v, 4);
        v += __shfl_xor(v, 8);
        numacc[r] = v;
    }
    if (lr == 0) {
#pragma unroll
        for (int r = 0; r < 8; ++r) {
            const int i = (r >> 2) * 16 + quad * 4 + (r & 3);
            numout[((size_t)bh * N_ + i0 + i) * 68 + dd] = numacc[r];
        }
    }
}

// ---------------------------------------------------------------------------
// Kernel 4: out[b,n,h*64+d] = num[bh,n,d] / num[bh,n,64]
// ---------------------------------------------------------------------------
__global__ __launch_bounds__(256) void finalize_kernel(const float* __restrict__ numw,
                                                       float* __restrict__ out) {
    const int o = blockIdx.x * 256 + threadIdx.x;
    const int b = o / (N_ * C_);
    const int rem = o - b * (N_ * C_);
    const int n = rem >> 8;
    const int cc = rem & 255;
    const int h = cc >> 6, d = cc & 63;
    const float* base = numw + (((size_t)b * H_ + h) * N_ + n) * 68;
    out[o] = base[d] / base[64];
}

extern "C" void kernel_launch(void* const* d_in, const int* in_sizes, int n_in,
                              void* d_out, int out_size, void* d_ws, size_t ws_size,
                              hipStream_t stream) {
    const float* x = (const float*)d_in[0];
    const float* W = (const float*)d_in[1];
    float* ws    = (float*)d_ws;
    float* proj  = ws;                         // 5*TSZ f32
    float* ecd   = ws + 5 * TSZ;               // ESZ f32
    float* numw  = ecd + ESZ;                  // 8*384*68 f32 = 208896
    f16*   eabt  = (f16*)(numw + NBH * N_ * 68);  // ESZ f16
    f16*   eef   = eabt + ESZ;                 // ESZ f16
    // total ~14.2 MB of d_ws

    proj_kernel<<<dim3(12, 20), 256, 0, stream>>>(x, W, proj);
    logits_kernel<<<dim3(6, 6, 24), 256, 0, stream>>>(proj, eabt, ecd, eef);
    triplet_mfma_kernel<<<dim3(12, 17, 8), 256, 0, stream>>>(
        eabt, ecd, eef, proj + 3 * TSZ, proj + 4 * TSZ, numw);
    finalize_kernel<<<dim3(768), 256, 0, stream>>>(numw, (float*)d_out);
}

// Round 7
// 270.363 us; speedup vs baseline: 5.3822x; 1.2652x over previous
//
#include <hip/hip_runtime.h>
#include <math.h>

#define B_  2
#define N_  384
#define C_  256
#define H_  4
#define D_  64
#define NBH (B_*H_)            // 8
#define TSZ (NBH*N_*D_)        // 196608 floats per projected tensor [bh][n][d]
#define ESZ (NBH*N_*N_)        // 1179648 elems per logit matrix [bh][i][j]
#define SCALE 0.125f           // D^-0.5
#define PIT 72                 // padded LDS pitch in f16 (144B) -> 2-way max bank alias

typedef _Float16 f16;
typedef f16  f16x8 __attribute__((ext_vector_type(8)));
typedef f16  f16x4 __attribute__((ext_vector_type(4)));
typedef float f32x4 __attribute__((ext_vector_type(4)));

// ---------------------------------------------------------------------------
// Kernel 1: projection (unchanged). proj[t][bh][n][d], t in {a,b,c,v1,v2}, f32.
// ---------------------------------------------------------------------------
__global__ __launch_bounds__(256) void proj_kernel(const float* __restrict__ x,
                                                   const float* __restrict__ W,
                                                   float* __restrict__ proj) {
    __shared__ float Xs[32][68];
    __shared__ float Ws[32][68];
    const int tid = threadIdx.x;
    const int tx = tid & 15, ty = tid >> 4;
    const int m0 = blockIdx.x * 64;
    const int c0 = blockIdx.y * 64;
    const int t  = c0 >> 8;
    const int wbase = ((t >= 3) ? (t + 3) : t) * 256;

    float acc[4][4] = {{0.f}};
    for (int k0 = 0; k0 < 256; k0 += 32) {
        __syncthreads();
#pragma unroll
        for (int l = 0; l < 8; ++l) {
            const int idx = l * 256 + tid;
            const int mi = idx >> 5, kk = idx & 31;
            Xs[kk][mi] = x[(m0 + mi) * 256 + k0 + kk];
            const int rem = (c0 + mi) & 255;
            Ws[kk][mi] = W[(wbase + rem) * 256 + k0 + kk];
        }
        __syncthreads();
#pragma unroll
        for (int kk = 0; kk < 32; ++kk) {
            const float4 xf = *(const float4*)&Xs[kk][ty * 4];
            const float4 wf = *(const float4*)&Ws[kk][tx * 4];
            const float xa[4] = {xf.x, xf.y, xf.z, xf.w};
            const float wa[4] = {wf.x, wf.y, wf.z, wf.w};
#pragma unroll
            for (int q = 0; q < 4; ++q)
#pragma unroll
                for (int p = 0; p < 4; ++p)
                    acc[q][p] += xa[q] * wa[p];
        }
    }
#pragma unroll
    for (int q = 0; q < 4; ++q) {
        const int r = m0 + ty * 4 + q;
        const int b = r / N_;
        const int n = r - b * N_;
#pragma unroll
        for (int p = 0; p < 4; ++p) {
            const int rem = (c0 + tx * 4 + p) & 255;
            const int h = rem >> 6, d = rem & 63;
            proj[t * TSZ + ((b * H_ + h) * N_ + n) * D_ + d] = acc[q][p];
        }
    }
}

// ---------------------------------------------------------------------------
// Kernel 2: exp-logit matrices, mixed-dtype outputs (unchanged).
// ---------------------------------------------------------------------------
__global__ __launch_bounds__(256) void logits_kernel(const float* __restrict__ proj,
                                                     f16* __restrict__ eabt16,
                                                     float* __restrict__ ecd,
                                                     f16* __restrict__ eef16) {
    __shared__ float Xs[32][68];
    __shared__ float Ys[32][68];
    const int tid = threadIdx.x;
    const int tx = tid & 15, ty = tid >> 4;
    const int i0 = blockIdx.x * 64, j0 = blockIdx.y * 64;
    const int q  = blockIdx.z >> 3;
    const int bh = blockIdx.z & 7;
    const int xt = q;
    const int yt = (q == 2) ? 0 : (q + 1);
    const float* Xp = proj + xt * TSZ + bh * N_ * D_;
    const float* Yp = proj + yt * TSZ + bh * N_ * D_;

    float acc[4][4] = {{0.f}};
    for (int k0 = 0; k0 < 64; k0 += 32) {
        __syncthreads();
#pragma unroll
        for (int l = 0; l < 8; ++l) {
            const int idx = l * 256 + tid;
            const int mi = idx >> 5, kk = idx & 31;
            Xs[kk][mi] = Xp[(i0 + mi) * 64 + k0 + kk];
            Ys[kk][mi] = Yp[(j0 + mi) * 64 + k0 + kk];
        }
        __syncthreads();
#pragma unroll
        for (int kk = 0; kk < 32; ++kk) {
            const float4 xf = *(const float4*)&Xs[kk][ty * 4];
            const float4 yf = *(const float4*)&Ys[kk][tx * 4];
            const float xa[4] = {xf.x, xf.y, xf.z, xf.w};
            const float ya[4] = {yf.x, yf.y, yf.z, yf.w};
#pragma unroll
            for (int qq = 0; qq < 4; ++qq)
#pragma unroll
                for (int p = 0; p < 4; ++p)
                    acc[qq][p] += xa[qq] * ya[p];
        }
    }
#pragma unroll
    for (int qq = 0; qq < 4; ++qq)
#pragma unroll
        for (int p = 0; p < 4; ++p) {
            const float e = expf(acc[qq][p] * SCALE);
            const int ii = i0 + ty * 4 + qq;
            const int jj = j0 + tx * 4 + p;
            if (q == 0)      eabt16[(size_t)bh * N_ * N_ + jj * N_ + ii] = (f16)e;
            else if (q == 1) ecd   [(size_t)bh * N_ * N_ + ii * N_ + jj] = e;
            else             eef16 [(size_t)bh * N_ * N_ + ii * N_ + jj] = (f16)e;
        }
}

// ---------------------------------------------------------------------------
// Kernel 3 (dominant), MFMA f16.
// Round-7: round-0's data paths and LDS layout BYTE-FOR-BYTE (PIT=72 pad,
// whole-block v1s, v2k, same staging patterns, same barrier structure --
// the only shape verified to compile at 96 VGPR). ONE change: 512-thread
// blocks, 8 waves = (d-slot 0..3) x (i-half 0..1). Each wave does HALF of
// round-0's per-wave work (af[2][2], numacc[8] -> lower VGPR demand), the
// block does the same total work on the SAME 62464 B LDS. Residency:
// LDS-limited 2 blocks/CU x 8 waves = 16 waves/CU = 4 waves/SIMD --
// double round-0 -- without touching the register-pressure knobs that
// exploded in rounds 1/3/5/6.
// ---------------------------------------------------------------------------
__global__ __launch_bounds__(512) void triplet_mfma_kernel(
        const f16*  __restrict__ eabt,   // [bh][j][i]
        const float* __restrict__ ecd,   // [bh][i][k]
        const f16*  __restrict__ eef,    // [bh][j][k]
        const float* __restrict__ v1,    // [bh][n][64]
        const float* __restrict__ v2,    // [bh][n][64]
        float* __restrict__ numout) {    // [bh][i][68]
    __shared__ __align__(16) unsigned char smem_raw[62464];
    f16*   us   = (f16*)smem_raw;                    // 4 * 64*PIT f16   = 36864 B
    f16*   es   = us + 4 * 64 * PIT;                 // 64*PIT f16       =  9216 B
    f16*   abts = es + 64 * PIT;                     // 64*PIT f16       =  9216 B
    float* v1s  = (float*)(smem_raw + 55296);        // 384*4 f32        =  6144 B
    float* v2k  = (float*)(smem_raw + 61440);        // 4*64 f32         =  1024 B

    const int tid  = threadIdx.x;        // 0..511
    const int lane = tid & 63;
    const int w    = tid >> 6;           // wave id 0..7
    const int ds   = w & 3;              // d slot 0..3
    const int ih   = w >> 2;             // i half 0..1
    const int quad = lane >> 4;
    const int lr   = lane & 15;
    const int i0 = blockIdx.x * 64;
    const int dg = blockIdx.y;           // 0..16
    const int bh = blockIdx.z;
    const int dd = dg * 4 + ds;          // 0..67 (>=64: denominator)

    const f16*   eabtb = eabt + (size_t)bh * N_ * N_;
    const float* ecdb  = ecd  + (size_t)bh * N_ * N_;
    const f16*   eefb  = eef  + (size_t)bh * N_ * N_;
    const float* v1b   = v1 + (size_t)bh * N_ * D_;
    const float* v2b   = v2 + (size_t)bh * N_ * D_;

    // stage v1 columns for the 4 d-slots: v1s[j*4 + c]
#pragma unroll
    for (int it = 0; it < 3; ++it) {
        const int id = it * 512 + tid;          // 0..1535
        const int j = id >> 2, c = id & 3;
        const int d2 = dg * 4 + c;
        v1s[id] = (d2 < 64) ? v1b[j * 64 + d2] : 1.0f;
    }

    float numacc[8];
#pragma unroll
    for (int r = 0; r < 8; ++r) numacc[r] = 0.f;

    const f32x4 zero4 = {0.f, 0.f, 0.f, 0.f};

    for (int kt = 0; kt < 6; ++kt) {
        const int k0 = kt * 64;
        __syncthreads();                 // prior readers of us/v2k done
        // stage v2 chunk: v2k[c*64 + k] (first 256 threads)
        if (tid < 256) {
            const int c = tid >> 6, k = tid & 63;
            const int d2 = dg * 4 + c;
            v2k[c * 64 + k] = (d2 < 64) ? v2b[(k0 + k) * 64 + d2] : 1.0f;
        }
        __syncthreads();
        // build U16[d][64i][PIT k] = f16(eCD * v2col)  (512 threads, 2 its)
#pragma unroll
        for (int it = 0; it < 2; ++it) {
            const int row  = it * 32 + (tid >> 4);
            const int kcol = (tid & 15) * 4;
            const float4 c4 = *(const float4*)&ecdb[(i0 + row) * N_ + k0 + kcol];
#pragma unroll
            for (int d = 0; d < 4; ++d) {
                const float4 w4 = *(const float4*)&v2k[d * 64 + kcol];
                union { f16 h[4]; unsigned long long u; } pk;
                pk.h[0] = (f16)(c4.x * w4.x);
                pk.h[1] = (f16)(c4.y * w4.y);
                pk.h[2] = (f16)(c4.z * w4.z);
                pk.h[3] = (f16)(c4.w * w4.w);
                *(unsigned long long*)(us + d * 64 * PIT + row * PIT + kcol) = pk.u;
            }
        }
        __syncthreads();
        // A-frags for this wave's (d-slot, i-half): 2 i-subtiles x 2 k-halves
        f16x8 af[2][2];
#pragma unroll
        for (int isub = 0; isub < 2; ++isub)
#pragma unroll
            for (int ks = 0; ks < 2; ++ks)
                af[isub][ks] = *(const f16x8*)(us + ds * 64 * PIT +
                                               ((ih * 2 + isub) * 16 + lr) * PIT +
                                               (ks * 4 + quad) * 8);

        for (int jt = 0; jt < 6; ++jt) {
            const int j0 = jt * 64;
            __syncthreads();             // prior readers of es/abts done
            {   // stage eEF / eABt tiles (512 threads, single pass)
                const int row = tid >> 3;          // 0..63
                const int blk = tid & 7;
                *(uint4*)(es   + row * PIT + blk * 8) =
                    *(const uint4*)(eefb  + (j0 + row) * N_ + k0 + blk * 8);
                *(uint4*)(abts + row * PIT + blk * 8) =
                    *(const uint4*)(eabtb + (j0 + row) * N_ + i0 + blk * 8);
            }
            __syncthreads();
            // MFMA + immediate fold of the partial R tile
#pragma unroll
            for (int js = 0; js < 4; ++js) {
                const f16x8 bf0 = *(const f16x8*)(es + (js * 16 + lr) * PIT + quad * 8);
                const f16x8 bf1 = *(const f16x8*)(es + (js * 16 + lr) * PIT + (4 + quad) * 8);
                const float v1v = v1s[(j0 + js * 16 + lr) * 4 + ds];
#pragma unroll
                for (int isub = 0; isub < 2; ++isub) {
                    f32x4 t;
                    t = __builtin_amdgcn_mfma_f32_16x16x32_f16(af[isub][0], bf0, zero4, 0, 0, 0);
                    t = __builtin_amdgcn_mfma_f32_16x16x32_f16(af[isub][1], bf1, t, 0, 0, 0);
                    const f16x4 ab = *(const f16x4*)(abts + (js * 16 + lr) * PIT +
                                                     (ih * 2 + isub) * 16 + quad * 4);
#pragma unroll
                    for (int q = 0; q < 4; ++q)
                        numacc[isub * 4 + q] += (float)ab[q] * (v1v * t[q]);
                }
            }
        }
    }
    // reduce the j-residues (low 4 lane bits) and write
#pragma unroll
    for (int r = 0; r < 8; ++r) {
        float v = numacc[r];
        v += __shfl_xor(v, 1);
        v += __shfl_xor(v, 2);
        v += __shfl_xor(v, 4);
        v += __shfl_xor(v, 8);
        numacc[r] = v;
    }
    if (lr == 0) {
#pragma unroll
        for (int r = 0; r < 8; ++r) {
            const int i = (ih * 2 + (r >> 2)) * 16 + quad * 4 + (r & 3);
            numout[((size_t)bh * N_ + i0 + i) * 68 + dd] = numacc[r];
        }
    }
}

// ---------------------------------------------------------------------------
// Kernel 4: out[b,n,h*64+d] = num[bh,n,d] / num[bh,n,64]
// ---------------------------------------------------------------------------
__global__ __launch_bounds__(256) void finalize_kernel(const float* __restrict__ numw,
                                                       float* __restrict__ out) {
    const int o = blockIdx.x * 256 + threadIdx.x;
    const int b = o / (N_ * C_);
    const int rem = o - b * (N_ * C_);
    const int n = rem >> 8;
    const int cc = rem & 255;
    const int h = cc >> 6, d = cc & 63;
    const float* base = numw + (((size_t)b * H_ + h) * N_ + n) * 68;
    out[o] = base[d] / base[64];
}

extern "C" void kernel_launch(void* const* d_in, const int* in_sizes, int n_in,
                              void* d_out, int out_size, void* d_ws, size_t ws_size,
                              hipStream_t stream) {
    const float* x = (const float*)d_in[0];
    const float* W = (const float*)d_in[1];
    float* ws    = (float*)d_ws;
    float* proj  = ws;                         // 5*TSZ f32
    float* ecd   = ws + 5 * TSZ;               // ESZ f32
    float* numw  = ecd + ESZ;                  // 8*384*68 f32 = 208896
    f16*   eabt  = (f16*)(numw + NBH * N_ * 68);  // ESZ f16
    f16*   eef   = eabt + ESZ;                 // ESZ f16
    // total ~14.2 MB of d_ws

    proj_kernel<<<dim3(12, 20), 256, 0, stream>>>(x, W, proj);
    logits_kernel<<<dim3(6, 6, 24), 256, 0, stream>>>(proj, eabt, ecd, eef);
    triplet_mfma_kernel<<<dim3(6, 17, 8), 512, 0, stream>>>(
        eabt, ecd, eef, proj + 3 * TSZ, proj + 4 * TSZ, numw);
    finalize_kernel<<<dim3(768), 256, 0, stream>>>(numw, (float*)d_out);
}